// Round 1
// baseline (107.418 us; speedup 1.0000x reference)
//
#include <hip/hip_runtime.h>
#include <hip/hip_bf16.h>

// Problem constants
#define B_    16
#define T_    2048
#define H_    512
#define BT_   32768      // B*T tokens
#define DIN   80         // obs 64 + act 16
#define DPAD  96         // padded K for embed GEMM (3 x 32)
#define L_    64         // scan chunk length
#define C_    32         // chunks per batch (T/L)
#define O_    64         // output dim

typedef __attribute__((ext_vector_type(8))) short short8;
typedef __attribute__((ext_vector_type(4))) float f32x4;

__device__ __forceinline__ float bf2f(unsigned short u) {
  union { unsigned int i; float f; } x; x.i = ((unsigned int)u) << 16; return x.f;
}
__device__ __forceinline__ unsigned short f2bf(float f) {
  union { float f; unsigned int i; } x; x.f = f;
  unsigned int r = x.i + 0x7fffu + ((x.i >> 16) & 1u);
  return (unsigned short)(r >> 16);
}

// ---------------------------------------------------------------------------
// Generic bf16 MFMA GEMM: C[M,N] = A[M,K] @ Bt[N,K]^T (+bias, optional ReLU)
// m97-style: 128-wide tiles, single-buffered LDS, global_load_lds width=16,
// 4 waves in 2x2, each wave FMxFN fragments of 16x16, K-step 32.
// ---------------------------------------------------------------------------
template<int BM, int BN, int BK, int RELU, int BIAS, int OUTBF>
__global__ __launch_bounds__(256) void gemm_bt(
    const unsigned short* __restrict__ A, const unsigned short* __restrict__ Bt,
    const float* __restrict__ bias, void* __restrict__ Cv,
    int M, int N, int K)
{
  constexpr int WAVES_N = 2;
  constexpr int WM = BM / 2, WN = BN / WAVES_N;
  constexpr int FM = WM / 16, FN = WN / 16;
  constexpr int A_BYTES = BM * BK * 2;
  constexpr int B_BYTES = BN * BK * 2;
  constexpr int TOT = A_BYTES + B_BYTES;
  constexpr int ROUNDS = TOT / 4096;   // 256 threads x 16B per round
  __shared__ unsigned short lds[TOT / 2];

  const int tid  = threadIdx.x;
  const int lane = tid & 63;
  const int wid  = tid >> 6;
  const int wr   = wid >> 1, wc = wid & 1;
  const int nb   = N / BN;
  const int mt   = (int)blockIdx.x / nb, nt = (int)blockIdx.x % nb;
  const int row0 = mt * BM, col0 = nt * BN;

  f32x4 acc[FM][FN];
  #pragma unroll
  for (int m = 0; m < FM; ++m)
    #pragma unroll
    for (int n = 0; n < FN; ++n) acc[m][n] = f32x4{0.f, 0.f, 0.f, 0.f};

  for (int k0 = 0; k0 < K; k0 += BK) {
    #pragma unroll
    for (int r = 0; r < ROUNDS; ++r) {
      const int o = r * 4096 + tid * 16;     // byte offset in LDS (linear)
      const unsigned short* gsrc;
      if (o < A_BYTES) {
        const int idx = o >> 1;
        const int row = idx / BK, kk = idx % BK;
        gsrc = A + (size_t)(row0 + row) * K + (k0 + kk);
      } else {
        const int idx = (o - A_BYTES) >> 1;
        const int row = idx / BK, kk = idx % BK;
        gsrc = Bt + (size_t)(col0 + row) * K + (k0 + kk);
      }
      __builtin_amdgcn_global_load_lds(
          (const __attribute__((address_space(1))) void*)gsrc,
          (__attribute__((address_space(3))) void*)((char*)lds + o),
          16, 0, 0);
    }
    __syncthreads();   // compiler emits vmcnt(0) drain before barrier

    const unsigned short* pA = lds + (wr * WM + (lane & 15)) * BK + ((lane >> 4) * 8);
    const unsigned short* pB = lds + (A_BYTES / 2) + (wc * WN + (lane & 15)) * BK + ((lane >> 4) * 8);
    short8 af[FM], bfr[FN];
    #pragma unroll
    for (int m = 0; m < FM; ++m) af[m] = *(const short8*)(pA + m * 16 * BK);
    #pragma unroll
    for (int n = 0; n < FN; ++n) bfr[n] = *(const short8*)(pB + n * 16 * BK);
    #pragma unroll
    for (int m = 0; m < FM; ++m)
      #pragma unroll
      for (int n = 0; n < FN; ++n)
        acc[m][n] = __builtin_amdgcn_mfma_f32_16x16x32_bf16(af[m], bfr[n], acc[m][n], 0, 0, 0);
    __syncthreads();
  }

  // Epilogue. D[r][c]: c = lane&15, r = (lane>>4)*4 + e  (m89-verified)
  const int cl = lane & 15, rg = (lane >> 4) * 4;
  #pragma unroll
  for (int m = 0; m < FM; ++m) {
    #pragma unroll
    for (int n = 0; n < FN; ++n) {
      #pragma unroll
      for (int e2 = 0; e2 < 4; ++e2) {
        const int gr = row0 + wr * WM + m * 16 + rg + e2;
        const int gc = col0 + wc * WN + n * 16 + cl;
        float v = acc[m][n][e2];
        if (BIAS) v += bias[gc];
        if (RELU) v = fmaxf(v, 0.f);
        if (OUTBF) ((unsigned short*)Cv)[(size_t)gr * N + gc] = f2bf(v);
        else       ((float*)Cv)[(size_t)gr * N + gc] = v;
      }
    }
  }
}

// ---------------------------------------------------------------------------
// Prep kernels
// ---------------------------------------------------------------------------
__global__ __launch_bounds__(256) void prep_x(
    const float* __restrict__ obs, const float* __restrict__ act,
    unsigned short* __restrict__ xb)
{
  const int idx = blockIdx.x * 256 + threadIdx.x;   // BT_*DPAD
  const int d = idx % DPAD, n = idx / DPAD;
  float val = 0.f;
  if (d < 64)      val = obs[n * 64 + d];
  else if (d < 80) val = act[n * 16 + (d - 64)];
  xb[idx] = f2bf(val);
}

#define WE_N  (H_ * DPAD)            // 49152
#define WB_N  (H_ * H_)              // 262144
#define WO_N  (O_ * H_)              // 32768
#define PREP_TOT (WE_N + WB_N + WO_N + H_)

__global__ __launch_bounds__(256) void prep_w(
    const float* __restrict__ W_e, const float* __restrict__ W_B,
    const float* __restrict__ W_out, const float* __restrict__ a_raw,
    unsigned short* __restrict__ Web, unsigned short* __restrict__ WBb,
    unsigned short* __restrict__ Woutb, float* __restrict__ aarr,
    float* __restrict__ powa)
{
  const int idx = blockIdx.x * 256 + threadIdx.x;
  if (idx < WE_N) {
    const int h = idx / DPAD, d = idx % DPAD;
    Web[idx] = f2bf(d < DIN ? W_e[h * DIN + d] : 0.f);
  } else if (idx < WE_N + WB_N) {
    const int j = idx - WE_N;
    WBb[j] = f2bf(W_B[j]);
  } else if (idx < WE_N + WB_N + WO_N) {
    const int j = idx - (WE_N + WB_N);
    Woutb[j] = f2bf(W_out[j]);
  } else if (idx < PREP_TOT) {
    const int h = idx - (WE_N + WB_N + WO_N);
    const float a = tanhf(a_raw[h]);
    aarr[h] = a;
    float p = a;
    #pragma unroll 8
    for (int i = 0; i < L_; ++i) { powa[i * H_ + h] = p; p *= a; }  // a^(i+1)
  }
}

// ---------------------------------------------------------------------------
// Chunked diagonal scan
// ---------------------------------------------------------------------------
// Pass 1: per (b, chunk) local scan. 512 blocks, thread owns 2 adjacent h.
__global__ __launch_bounds__(256) void scan_local(
    const unsigned int* __restrict__ v, unsigned int* __restrict__ s,
    float* __restrict__ e, const float* __restrict__ aarr)
{
  const int b = blockIdx.x >> 5, c = blockIdx.x & 31;
  const int tid = threadIdx.x;
  const int h0 = tid * 2;
  const float a0 = aarr[h0], a1 = aarr[h0 + 1];
  const size_t base = ((size_t)(b * T_ + c * L_)) * (H_ / 2) + tid;
  const unsigned int* vp = v + base;
  unsigned int* sp = s + base;
  float s0 = 0.f, s1 = 0.f;
  #pragma unroll 8
  for (int i = 0; i < L_; ++i) {
    const unsigned int pv = vp[(size_t)i * (H_ / 2)];
    s0 = fmaf(a0, s0, bf2f((unsigned short)(pv & 0xffff)));
    s1 = fmaf(a1, s1, bf2f((unsigned short)(pv >> 16)));
    sp[(size_t)i * (H_ / 2)] = (unsigned int)f2bf(s0) | ((unsigned int)f2bf(s1) << 16);
  }
  e[(size_t)blockIdx.x * H_ + h0]     = s0;
  e[(size_t)blockIdx.x * H_ + h0 + 1] = s1;
}

// Pass 2: serial carry over 32 chunks per (b,h). P[b,c,h] = carry INTO chunk c.
__global__ __launch_bounds__(256) void carry_scan(
    const float* __restrict__ e, float* __restrict__ P,
    const float* __restrict__ aarr)
{
  const int idx = blockIdx.x * 256 + threadIdx.x;  // B_*H_ = 8192
  const int b = idx >> 9, h = idx & (H_ - 1);
  const float a = aarr[h];
  float aL = a * a; aL *= aL; aL *= aL; aL *= aL; aL *= aL; aL *= aL;  // a^64
  float S = 0.f;
  for (int c = 0; c < C_; ++c) {
    const size_t o = ((size_t)(b * C_ + c)) * H_ + h;
    P[o] = S;
    S = fmaf(aL, S, e[o]);
  }
}

// Pass 3: s[b,t,h] = s_local + a^{(t%L)+1} * P[b, t/L, h]
__global__ __launch_bounds__(256) void fixup(
    unsigned int* __restrict__ s, const float* __restrict__ P,
    const float* __restrict__ powa)
{
  const int gid = blockIdx.x * 256 + threadIdx.x;   // BT_*H_/2
  const int hp = gid & (H_ / 2 - 1), h0 = hp * 2;
  const int tt = gid >> 8;           // b*T + t
  const int b = tt >> 11, t = tt & (T_ - 1);
  const int c = t >> 6, i = t & (L_ - 1);
  const unsigned int sv = s[gid];
  const size_t po = ((size_t)(b * C_ + c)) * H_ + h0;
  const float p0 = P[po], p1 = P[po + 1];
  const float w0 = powa[i * H_ + h0], w1 = powa[i * H_ + h0 + 1];
  const float s0 = bf2f((unsigned short)(sv & 0xffff)) + w0 * p0;
  const float s1 = bf2f((unsigned short)(sv >> 16))    + w1 * p1;
  s[gid] = (unsigned int)f2bf(s0) | ((unsigned int)f2bf(s1) << 16);
}

// ---------------------------------------------------------------------------
extern "C" void kernel_launch(void* const* d_in, const int* in_sizes, int n_in,
                              void* d_out, int out_size, void* d_ws, size_t ws_size,
                              hipStream_t stream)
{
  const float* obs   = (const float*)d_in[0];
  const float* act   = (const float*)d_in[1];
  const float* W_e   = (const float*)d_in[2];
  const float* b_e   = (const float*)d_in[3];
  const float* a_raw = (const float*)d_in[4];
  const float* W_B   = (const float*)d_in[5];
  const float* W_out = (const float*)d_in[6];
  const float* b_out = (const float*)d_in[7];
  float* y = (float*)d_out;

  char* w = (char*)d_ws;
  auto carve = [&](size_t bytes) {
    char* p = w; w += (bytes + 255) & ~(size_t)255; return p;
  };
  unsigned short* xb    = (unsigned short*)carve((size_t)BT_ * DPAD * 2);  // 6.3 MB
  unsigned short* Web   = (unsigned short*)carve((size_t)H_ * DPAD * 2);
  unsigned short* WBb   = (unsigned short*)carve((size_t)H_ * H_ * 2);
  unsigned short* Woutb = (unsigned short*)carve((size_t)O_ * H_ * 2);
  float*          aarr  = (float*)carve((size_t)H_ * 4);
  float*          powa  = (float*)carve((size_t)L_ * H_ * 4);
  unsigned short* u     = (unsigned short*)carve((size_t)BT_ * H_ * 2);    // 33.5 MB (reused as s)
  unsigned short* v     = (unsigned short*)carve((size_t)BT_ * H_ * 2);    // 33.5 MB
  float*          e     = (float*)carve((size_t)B_ * C_ * H_ * 4);
  float*          P     = (float*)carve((size_t)B_ * C_ * H_ * 4);

  // Prep: concat+pad x -> bf16; weights -> bf16; a = tanh(a_raw); power table
  prep_x<<<BT_ * DPAD / 256, 256, 0, stream>>>(obs, act, xb);
  prep_w<<<(PREP_TOT + 255) / 256, 256, 0, stream>>>(W_e, W_B, W_out, a_raw,
                                                     Web, WBb, Woutb, aarr, powa);
  // u = relu(x @ W_e^T + b_e)   [32768, 512], K=96 (padded)
  gemm_bt<128, 128, 32, 1, 1, 1><<<(BT_ / 128) * (H_ / 128), 256, 0, stream>>>(
      xb, Web, b_e, u, BT_, H_, DPAD);
  // v = u @ W_B^T               [32768, 512], K=512
  gemm_bt<128, 128, 32, 0, 0, 1><<<(BT_ / 128) * (H_ / 128), 256, 0, stream>>>(
      u, WBb, nullptr, v, BT_, H_, H_);
  // chunked scan: local scans (s aliases u), carries, fixup
  scan_local<<<B_ * C_, 256, 0, stream>>>((const unsigned int*)v, (unsigned int*)u, e, aarr);
  carry_scan<<<(B_ * H_) / 256, 256, 0, stream>>>(e, P, aarr);
  fixup<<<(BT_ * H_ / 2) / 256, 256, 0, stream>>>((unsigned int*)u, P, powa);
  // y = s @ W_out^T + b_out     [32768, 64] fp32
  gemm_bt<128, 64, 32, 0, 1, 0><<<(BT_ / 128) * (O_ / 64), 256, 0, stream>>>(
      u, Woutb, b_out, y, BT_, O_, H_);
}

// Round 2
// 88.891 us; speedup vs baseline: 1.2084x; 1.2084x over previous
//
#include <hip/hip_runtime.h>
#include <hip/hip_bf16.h>

// Problem constants
#define B_    16
#define T_    2048
#define H_    512
#define BT_   32768      // B*T tokens
#define DIN   80         // obs 64 + act 16
#define DPAD  96         // padded K for embed GEMM (3 x 32)
#define L_    64         // scan chunk length
#define C_    32         // chunks per batch (T/L)
#define O_    64         // output dim
#define NCHUNK (BT_ / L_)  // 512 total chunks

typedef __attribute__((ext_vector_type(8))) short short8;
typedef __attribute__((ext_vector_type(4))) float f32x4;
typedef __attribute__((ext_vector_type(4))) float float4v;

__device__ __forceinline__ float bf2f(unsigned short u) {
  union { unsigned int i; float f; } x; x.i = ((unsigned int)u) << 16; return x.f;
}
__device__ __forceinline__ unsigned short f2bf(float f) {
  union { float f; unsigned int i; } x; x.f = f;
  unsigned int r = x.i + 0x7fffu + ((x.i >> 16) & 1u);
  return (unsigned short)(r >> 16);
}

// ---------------------------------------------------------------------------
// Generic bf16 MFMA GEMM: C[M,N] = A[M,K] @ Bt[N,K]^T (+bias, optional ReLU)
// m97-style: 128x128 tile, single-buffered LDS, global_load_lds width=16,
// 4 waves in 2x2, each wave 4x4 fragments of 16x16, K-step 32.
// CE=1: additionally emit chunk-end weighted sums e[chunk, h] from fp32 acc.
// ---------------------------------------------------------------------------
template<int BM, int BN, int BK, int RELU, int BIAS, int OUTBF, int CE>
__global__ __launch_bounds__(256) void gemm_bt(
    const unsigned short* __restrict__ A, const unsigned short* __restrict__ Bt,
    const float* __restrict__ bias, void* __restrict__ Cv,
    int M, int N, int K,
    const float* __restrict__ powa,   // [16][H]: a^(i+1), i=0..15  (CE only)
    float* __restrict__ e)            // [NCHUNK][H]                (CE only)
{
  constexpr int WAVES_N = 2;
  constexpr int WM = BM / 2, WN = BN / WAVES_N;
  constexpr int FM = WM / 16, FN = WN / 16;
  constexpr int A_BYTES = BM * BK * 2;
  constexpr int B_BYTES = BN * BK * 2;
  constexpr int TOT = A_BYTES + B_BYTES;
  constexpr int ROUNDS = TOT / 4096;   // 256 threads x 16B per round
  __shared__ unsigned short lds[TOT / 2];

  const int tid  = threadIdx.x;
  const int lane = tid & 63;
  const int wid  = tid >> 6;
  const int wr   = wid >> 1, wc = wid & 1;
  const int nb   = N / BN;
  const int mt   = (int)blockIdx.x / nb, nt = (int)blockIdx.x % nb;
  const int row0 = mt * BM, col0 = nt * BN;

  f32x4 acc[FM][FN];
  #pragma unroll
  for (int m = 0; m < FM; ++m)
    #pragma unroll
    for (int n = 0; n < FN; ++n) acc[m][n] = f32x4{0.f, 0.f, 0.f, 0.f};

  for (int k0 = 0; k0 < K; k0 += BK) {
    #pragma unroll
    for (int r = 0; r < ROUNDS; ++r) {
      const int o = r * 4096 + tid * 16;     // byte offset in LDS (linear)
      const unsigned short* gsrc;
      if (o < A_BYTES) {
        const int idx = o >> 1;
        const int row = idx / BK, kk = idx % BK;
        gsrc = A + (size_t)(row0 + row) * K + (k0 + kk);
      } else {
        const int idx = (o - A_BYTES) >> 1;
        const int row = idx / BK, kk = idx % BK;
        gsrc = Bt + (size_t)(col0 + row) * K + (k0 + kk);
      }
      __builtin_amdgcn_global_load_lds(
          (const __attribute__((address_space(1))) void*)gsrc,
          (__attribute__((address_space(3))) void*)((char*)lds + o),
          16, 0, 0);
    }
    __syncthreads();

    const unsigned short* pA = lds + (wr * WM + (lane & 15)) * BK + ((lane >> 4) * 8);
    const unsigned short* pB = lds + (A_BYTES / 2) + (wc * WN + (lane & 15)) * BK + ((lane >> 4) * 8);
    short8 af[FM], bfr[FN];
    #pragma unroll
    for (int m = 0; m < FM; ++m) af[m] = *(const short8*)(pA + m * 16 * BK);
    #pragma unroll
    for (int n = 0; n < FN; ++n) bfr[n] = *(const short8*)(pB + n * 16 * BK);
    #pragma unroll
    for (int m = 0; m < FM; ++m)
      #pragma unroll
      for (int n = 0; n < FN; ++n)
        acc[m][n] = __builtin_amdgcn_mfma_f32_16x16x32_bf16(af[m], bfr[n], acc[m][n], 0, 0, 0);
    __syncthreads();
  }

  // Epilogue. D[r][c]: c = lane&15, r = (lane>>4)*4 + e2  (m89-verified)
  const int cl = lane & 15, rg = (lane >> 4) * 4;
  #pragma unroll
  for (int m = 0; m < FM; ++m) {
    #pragma unroll
    for (int n = 0; n < FN; ++n) {
      #pragma unroll
      for (int e2 = 0; e2 < 4; ++e2) {
        const int gr = row0 + wr * WM + m * 16 + rg + e2;
        const int gc = col0 + wc * WN + n * 16 + cl;
        float v = acc[m][n][e2];
        if (BIAS) v += bias[gc];
        if (RELU) v = fmaxf(v, 0.f);
        if (OUTBF) ((unsigned short*)Cv)[(size_t)gr * N + gc] = f2bf(v);
        else       ((float*)Cv)[(size_t)gr * N + gc] = v;
      }
    }
  }

  // Chunk-end e[chunk][h] = sum_{i=0..63} a^{63-i} * v_i  (wave wr owns one
  // 64-row chunk; requires WM==64, i.e. FM==4). Weight factorization:
  // a^{63-i} = a^{15-rg-e2} * (a^16)^{3-m} with i = m*16 + rg + e2.
  if (CE) {
    const int chunk = (row0 + wr * WM) >> 6;
    #pragma unroll
    for (int n = 0; n < FN; ++n) {
      const int h = col0 + wc * WN + n * 16 + cl;
      const float a16 = powa[15 * H_ + h];
      float ep = 0.f;
      #pragma unroll
      for (int e2 = 0; e2 < 4; ++e2) {
        const int k = 15 - rg - e2;    // 0..15
        const float wk = (k == 0) ? 1.f : powa[(size_t)(k - 1) * H_ + h];
        float hsum = acc[0][n][e2];                 // Horner over m
        hsum = fmaf(hsum, a16, acc[1][n][e2]);
        hsum = fmaf(hsum, a16, acc[2][n][e2]);
        hsum = fmaf(hsum, a16, acc[3][n][e2]);
        ep = fmaf(wk, hsum, ep);
      }
      ep += __shfl_xor(ep, 16);
      ep += __shfl_xor(ep, 32);
      if ((lane >> 4) == 0)
        e[(size_t)chunk * H_ + h] = ep;
    }
  }
}

// ---------------------------------------------------------------------------
// Prep kernels
// ---------------------------------------------------------------------------
// Each thread emits 8 bf16 (16B). DPAD=96 -> 12 groups of 8 per token.
__global__ __launch_bounds__(256) void prep_x(
    const float* __restrict__ obs, const float* __restrict__ act,
    unsigned short* __restrict__ xb)
{
  const int idx = blockIdx.x * 256 + threadIdx.x;   // BT_*12 threads
  const int g = idx % 12, n = idx / 12;
  float f[8];
  if (g < 8) {
    const float4v f0 = ((const float4v*)obs)[(size_t)n * 16 + g * 2];
    const float4v f1 = ((const float4v*)obs)[(size_t)n * 16 + g * 2 + 1];
    f[0]=f0[0]; f[1]=f0[1]; f[2]=f0[2]; f[3]=f0[3];
    f[4]=f1[0]; f[5]=f1[1]; f[6]=f1[2]; f[7]=f1[3];
  } else if (g < 10) {
    const float4v f0 = ((const float4v*)act)[(size_t)n * 4 + (g - 8) * 2];
    const float4v f1 = ((const float4v*)act)[(size_t)n * 4 + (g - 8) * 2 + 1];
    f[0]=f0[0]; f[1]=f0[1]; f[2]=f0[2]; f[3]=f0[3];
    f[4]=f1[0]; f[5]=f1[1]; f[6]=f1[2]; f[7]=f1[3];
  } else {
    #pragma unroll
    for (int i = 0; i < 8; ++i) f[i] = 0.f;
  }
  short8 o;
  #pragma unroll
  for (int i = 0; i < 8; ++i) o[i] = (short)f2bf(f[i]);
  *(short8*)(xb + (size_t)idx * 8) = o;
}

#define WE_N  (H_ * DPAD)            // 49152
#define WB_N  (H_ * H_)              // 262144
#define WO_N  (O_ * H_)              // 32768
#define PREP_TOT (WE_N + WB_N + WO_N + H_)

__global__ __launch_bounds__(256) void prep_w(
    const float* __restrict__ W_e, const float* __restrict__ W_B,
    const float* __restrict__ W_out, const float* __restrict__ a_raw,
    unsigned short* __restrict__ Web, unsigned short* __restrict__ WBb,
    unsigned short* __restrict__ Woutb, float* __restrict__ aarr,
    float* __restrict__ powa)
{
  const int idx = blockIdx.x * 256 + threadIdx.x;
  if (idx < WE_N) {
    const int h = idx / DPAD, d = idx % DPAD;
    Web[idx] = f2bf(d < DIN ? W_e[h * DIN + d] : 0.f);
  } else if (idx < WE_N + WB_N) {
    const int j = idx - WE_N;
    WBb[j] = f2bf(W_B[j]);
  } else if (idx < WE_N + WB_N + WO_N) {
    const int j = idx - (WE_N + WB_N);
    Woutb[j] = f2bf(W_out[j]);
  } else if (idx < PREP_TOT) {
    const int h = idx - (WE_N + WB_N + WO_N);
    const float a = tanhf(a_raw[h]);
    aarr[h] = a;
    float p = a;
    #pragma unroll
    for (int i = 0; i < 16; ++i) { powa[i * H_ + h] = p; p *= a; }  // a^(i+1)
  }
}

// ---------------------------------------------------------------------------
// Carry scan: serial over 32 chunks per (b,h). P[b,c,h] = carry INTO chunk c.
// ---------------------------------------------------------------------------
__global__ __launch_bounds__(256) void carry_scan(
    const float* __restrict__ e, float* __restrict__ P,
    const float* __restrict__ aarr)
{
  const int idx = blockIdx.x * 256 + threadIdx.x;  // B_*H_ = 8192
  const int b = idx >> 9, h = idx & (H_ - 1);
  const float a = aarr[h];
  float aL = a * a; aL *= aL; aL *= aL; aL *= aL; aL *= aL; aL *= aL;  // a^64
  float S = 0.f;
  for (int c = 0; c < C_; ++c) {
    const size_t o = ((size_t)(b * C_ + c)) * H_ + h;
    P[o] = S;
    S = fmaf(aL, S, e[o]);
  }
}

// ---------------------------------------------------------------------------
// Fused scan + out-projection. One block per chunk (512 blocks, 256 threads).
// Phase 1: diagonal scan of v over the 64-step chunk, init from P, writing
//          bf16 s-tile to XOR-swizzled LDS (row-major [64][512] would be a
//          16-way bank conflict on ds_read_b128 -> byte ^= (t&7)<<4, G4).
// Phase 2: y[64,64] = s[64,512] @ W_out[64,512]^T + b_out via MFMA; W_out
//          read from global (64KB, L2-hot across all 512 blocks).
// ---------------------------------------------------------------------------
__global__ __launch_bounds__(256) void scan_out(
    const unsigned int* __restrict__ v,      // bf16 pairs [BT, H/2]
    const float* __restrict__ P,             // [NCHUNK, H]
    const float* __restrict__ aarr,          // [H]
    const unsigned short* __restrict__ Wo,   // bf16 [O, H]
    const float* __restrict__ b_out,         // [O]
    float* __restrict__ y)                   // [BT, O] fp32
{
  __shared__ __align__(16) unsigned char sbytes[64 * 1024];
  const int blk = blockIdx.x;          // global chunk id = b*C + c
  const int tid = threadIdx.x;
  const int lane = tid & 63, w = tid >> 6;
  const int row_base = blk * L_;       // global token row of chunk start

  // Phase 1: scan. Thread owns h pair (2*tid, 2*tid+1).
  {
    const int h0 = tid * 2;
    const float a0 = aarr[h0], a1 = aarr[h0 + 1];
    float s0 = P[(size_t)blk * H_ + h0];
    float s1 = P[(size_t)blk * H_ + h0 + 1];
    const unsigned int* vp = v + (size_t)row_base * (H_ / 2) + tid;
    #pragma unroll 8
    for (int t = 0; t < L_; ++t) {
      const unsigned int pv = vp[(size_t)t * (H_ / 2)];
      s0 = fmaf(a0, s0, bf2f((unsigned short)(pv & 0xffff)));
      s1 = fmaf(a1, s1, bf2f((unsigned short)(pv >> 16)));
      const int byte = t * 1024 + ((tid * 4) ^ ((t & 7) << 4));
      *(unsigned int*)(sbytes + byte) =
          (unsigned int)f2bf(s0) | ((unsigned int)f2bf(s1) << 16);
    }
  }
  __syncthreads();

  // Phase 2: MFMA. Wave w: t-rows w*16..w*16+15, all 64 o-cols.
  f32x4 acc[4];
  #pragma unroll
  for (int n = 0; n < 4; ++n) acc[n] = f32x4{0.f, 0.f, 0.f, 0.f};
  const int r = w * 16 + (lane & 15);
  const int kof = (lane >> 4) * 8;
  #pragma unroll 4
  for (int k0 = 0; k0 < H_; k0 += 32) {
    const int byte = r * 1024 + (((k0 + kof) * 2) ^ ((r & 7) << 4));
    const short8 af = *(const short8*)(sbytes + byte);
    #pragma unroll
    for (int n = 0; n < 4; ++n) {
      const short8 bf = *(const short8*)(Wo + (size_t)(n * 16 + (lane & 15)) * H_ + k0 + kof);
      acc[n] = __builtin_amdgcn_mfma_f32_16x16x32_bf16(af, bf, acc[n], 0, 0, 0);
    }
  }
  const int cl = lane & 15, rg = (lane >> 4) * 4;
  #pragma unroll
  for (int n = 0; n < 4; ++n) {
    #pragma unroll
    for (int e2 = 0; e2 < 4; ++e2) {
      const int gr = row_base + w * 16 + rg + e2;
      const int gc = n * 16 + cl;
      y[(size_t)gr * O_ + gc] = acc[n][e2] + b_out[gc];
    }
  }
}

// ---------------------------------------------------------------------------
extern "C" void kernel_launch(void* const* d_in, const int* in_sizes, int n_in,
                              void* d_out, int out_size, void* d_ws, size_t ws_size,
                              hipStream_t stream)
{
  const float* obs   = (const float*)d_in[0];
  const float* act   = (const float*)d_in[1];
  const float* W_e   = (const float*)d_in[2];
  const float* b_e   = (const float*)d_in[3];
  const float* a_raw = (const float*)d_in[4];
  const float* W_B   = (const float*)d_in[5];
  const float* W_out = (const float*)d_in[6];
  const float* b_out = (const float*)d_in[7];
  float* y = (float*)d_out;

  char* w = (char*)d_ws;
  auto carve = [&](size_t bytes) {
    char* p = w; w += (bytes + 255) & ~(size_t)255; return p;
  };
  unsigned short* xb    = (unsigned short*)carve((size_t)BT_ * DPAD * 2);  // 6.3 MB
  unsigned short* Web   = (unsigned short*)carve((size_t)H_ * DPAD * 2);
  unsigned short* WBb   = (unsigned short*)carve((size_t)H_ * H_ * 2);
  unsigned short* Woutb = (unsigned short*)carve((size_t)O_ * H_ * 2);
  float*          aarr  = (float*)carve((size_t)H_ * 4);
  float*          powa  = (float*)carve((size_t)16 * H_ * 4);
  unsigned short* u     = (unsigned short*)carve((size_t)BT_ * H_ * 2);    // 33.5 MB
  unsigned short* v     = (unsigned short*)carve((size_t)BT_ * H_ * 2);    // 33.5 MB
  float*          e     = (float*)carve((size_t)NCHUNK * H_ * 4);
  float*          P     = (float*)carve((size_t)NCHUNK * H_ * 4);

  // Prep: concat+pad x -> bf16; weights -> bf16; a = tanh(a_raw); power table
  prep_x<<<BT_ * 12 / 256, 256, 0, stream>>>(obs, act, xb);
  prep_w<<<(PREP_TOT + 255) / 256, 256, 0, stream>>>(W_e, W_B, W_out, a_raw,
                                                     Web, WBb, Woutb, aarr, powa);
  // u = relu(x @ W_e^T + b_e)   [32768, 512], K=96 (padded)
  gemm_bt<128, 128, 32, 1, 1, 1, 0><<<(BT_ / 128) * (H_ / 128), 256, 0, stream>>>(
      xb, Web, b_e, u, BT_, H_, DPAD, nullptr, nullptr);
  // v = u @ W_B^T               [32768, 512], K=512; epilogue also emits e
  gemm_bt<128, 128, 32, 0, 0, 1, 1><<<(BT_ / 128) * (H_ / 128), 256, 0, stream>>>(
      u, WBb, nullptr, v, BT_, H_, H_, powa, e);
  // carries
  carry_scan<<<(B_ * H_) / 256, 256, 0, stream>>>(e, P, aarr);
  // fused scan + out-projection -> y
  scan_out<<<NCHUNK, 256, 0, stream>>>((const unsigned int*)v, P, aarr,
                                       Woutb, b_out, y);
}

// Round 3
// 79.280 us; speedup vs baseline: 1.3549x; 1.1212x over previous
//
#include <hip/hip_runtime.h>
#include <hip/hip_bf16.h>

// Problem constants
#define B_    16
#define T_    2048
#define H_    512
#define BT_   32768      // B*T tokens
#define DIN   80         // obs 64 + act 16
#define DPAD  96         // padded K for embed GEMM (3 x 32)
#define L_    64         // scan chunk length
#define C_    32         // chunks per batch (T/L)
#define O_    64         // output dim
#define NCHUNK (BT_ / L_)  // 512 total chunks

typedef __attribute__((ext_vector_type(8))) short short8;
typedef __attribute__((ext_vector_type(4))) float f32x4;
typedef __attribute__((ext_vector_type(4))) float float4v;

__device__ __forceinline__ float bf2f(unsigned short u) {
  union { unsigned int i; float f; } x; x.i = ((unsigned int)u) << 16; return x.f;
}
__device__ __forceinline__ unsigned short f2bf(float f) {
  union { float f; unsigned int i; } x; x.f = f;
  unsigned int r = x.i + 0x7fffu + ((x.i >> 16) & 1u);
  return (unsigned short)(r >> 16);
}

// ---------------------------------------------------------------------------
// Generic bf16 MFMA GEMM: C[M,N] = A[M,K] @ Bt[N,K]^T (+bias, optional ReLU)
// 128x128 tile, 4 waves 2x2, 16x16x32 bf16, K-step 32.
// 2-PHASE double-buffered pipeline (T3 minimum): stage tile t+1 via
// global_load_lds BEFORE computing tile t; one barrier per K-step. The
// __syncthreads() drain (vmcnt0+lgkmcnt0) then waits on a prefetch whose
// latency was hidden under the ds_read+MFMA of the current tile.
// XS=1: bijective XCD-aware blockIdx swizzle (requires gridDim%8==0) so the
// 4 N-tiles sharing an A-panel land on the same XCD's L2.
// CE=1: additionally emit chunk-end weighted sums e[chunk, h] from fp32 acc.
// ---------------------------------------------------------------------------
template<int BM, int BN, int BK, int RELU, int BIAS, int OUTBF, int CE, int XS>
__global__ __launch_bounds__(256) void gemm_bt(
    const unsigned short* __restrict__ A, const unsigned short* __restrict__ Bt,
    const float* __restrict__ bias, void* __restrict__ Cv,
    int M, int N, int K,
    const float* __restrict__ powa,   // [16][H]: a^(i+1), i=0..15  (CE only)
    float* __restrict__ e)            // [NCHUNK][H]                (CE only)
{
  constexpr int WAVES_N = 2;
  constexpr int WM = BM / 2, WN = BN / WAVES_N;
  constexpr int FM = WM / 16, FN = WN / 16;
  constexpr int A_BYTES = BM * BK * 2;
  constexpr int TOT = A_BYTES + BN * BK * 2;
  constexpr int ROUNDS = TOT / 4096;   // 256 threads x 16B per round
  __shared__ __align__(16) unsigned char ldsb[2 * TOT];

  const int tid  = threadIdx.x;
  const int lane = tid & 63;
  const int wid  = tid >> 6;
  const int wr   = wid >> 1, wc = wid & 1;

  int bid = (int)blockIdx.x;
  if (XS) {                       // bijective since gridDim.x % 8 == 0
    const int cpx = (int)gridDim.x >> 3;
    bid = (bid & 7) * cpx + (bid >> 3);
  }
  const int nb   = N / BN;
  const int mt   = bid / nb, nt = bid % nb;
  const int row0 = mt * BM, col0 = nt * BN;

  auto stage = [&](int k0, int buf) {
    #pragma unroll
    for (int r = 0; r < ROUNDS; ++r) {
      const int o = r * 4096 + tid * 16;     // byte offset within one buffer
      const unsigned short* gsrc;
      if (o < A_BYTES) {
        const int idx = o >> 1;
        const int row = idx / BK, kk = idx % BK;
        gsrc = A + (size_t)(row0 + row) * K + (k0 + kk);
      } else {
        const int idx = (o - A_BYTES) >> 1;
        const int row = idx / BK, kk = idx % BK;
        gsrc = Bt + (size_t)(col0 + row) * K + (k0 + kk);
      }
      __builtin_amdgcn_global_load_lds(
          (const __attribute__((address_space(1))) void*)gsrc,
          (__attribute__((address_space(3))) void*)(ldsb + buf * TOT + o),
          16, 0, 0);
    }
  };

  f32x4 acc[FM][FN];
  #pragma unroll
  for (int m = 0; m < FM; ++m)
    #pragma unroll
    for (int n = 0; n < FN; ++n) acc[m][n] = f32x4{0.f, 0.f, 0.f, 0.f};

  const int NT = K / BK;
  stage(0, 0);
  __syncthreads();
  int cur = 0;
  for (int t = 0; t < NT; ++t) {
    if (t + 1 < NT) stage((t + 1) * BK, cur ^ 1);   // prefetch next tile

    const unsigned short* base = (const unsigned short*)(ldsb + cur * TOT);
    const unsigned short* pA = base + (wr * WM + (lane & 15)) * BK + ((lane >> 4) * 8);
    const unsigned short* pB = base + (A_BYTES / 2) + (wc * WN + (lane & 15)) * BK + ((lane >> 4) * 8);
    short8 af[FM], bfr[FN];
    #pragma unroll
    for (int m = 0; m < FM; ++m) af[m] = *(const short8*)(pA + m * 16 * BK);
    #pragma unroll
    for (int n = 0; n < FN; ++n) bfr[n] = *(const short8*)(pB + n * 16 * BK);
    #pragma unroll
    for (int m = 0; m < FM; ++m)
      #pragma unroll
      for (int n = 0; n < FN; ++n)
        acc[m][n] = __builtin_amdgcn_mfma_f32_16x16x32_bf16(af[m], bfr[n], acc[m][n], 0, 0, 0);

    __syncthreads();   // drains vmcnt(0): prefetch of t+1 now resident
    cur ^= 1;
  }

  // Epilogue. D[r][c]: c = lane&15, r = (lane>>4)*4 + e2  (m89-verified)
  const int cl = lane & 15, rg = (lane >> 4) * 4;
  #pragma unroll
  for (int m = 0; m < FM; ++m) {
    #pragma unroll
    for (int n = 0; n < FN; ++n) {
      #pragma unroll
      for (int e2 = 0; e2 < 4; ++e2) {
        const int gr = row0 + wr * WM + m * 16 + rg + e2;
        const int gc = col0 + wc * WN + n * 16 + cl;
        float v = acc[m][n][e2];
        if (BIAS) v += bias[gc];
        if (RELU) v = fmaxf(v, 0.f);
        if (OUTBF) ((unsigned short*)Cv)[(size_t)gr * N + gc] = f2bf(v);
        else       ((float*)Cv)[(size_t)gr * N + gc] = v;
      }
    }
  }

  // Chunk-end e[chunk][h] = sum_{i=0..63} a^{63-i} * v_i  (wave wr owns one
  // 64-row chunk; requires WM==64). a^{63-i} = a^{15-rg-e2} * (a^16)^{3-m}.
  if (CE) {
    const int chunk = (row0 + wr * WM) >> 6;
    #pragma unroll
    for (int n = 0; n < FN; ++n) {
      const int h = col0 + wc * WN + n * 16 + cl;
      const float a16 = powa[15 * H_ + h];
      float ep = 0.f;
      #pragma unroll
      for (int e2 = 0; e2 < 4; ++e2) {
        const int k = 15 - rg - e2;    // 0..15
        const float wk = (k == 0) ? 1.f : powa[(size_t)(k - 1) * H_ + h];
        float hsum = acc[0][n][e2];                 // Horner over m
        hsum = fmaf(hsum, a16, acc[1][n][e2]);
        hsum = fmaf(hsum, a16, acc[2][n][e2]);
        hsum = fmaf(hsum, a16, acc[3][n][e2]);
        ep = fmaf(wk, hsum, ep);
      }
      ep += __shfl_xor(ep, 16);
      ep += __shfl_xor(ep, 32);
      if ((lane >> 4) == 0)
        e[(size_t)chunk * H_ + h] = ep;
    }
  }
}

// ---------------------------------------------------------------------------
// Prep kernels
// ---------------------------------------------------------------------------
// Each thread emits 8 bf16 (16B). DPAD=96 -> 12 groups of 8 per token.
__global__ __launch_bounds__(256) void prep_x(
    const float* __restrict__ obs, const float* __restrict__ act,
    unsigned short* __restrict__ xb)
{
  const int idx = blockIdx.x * 256 + threadIdx.x;   // BT_*12 threads
  const int g = idx % 12, n = idx / 12;
  float f[8];
  if (g < 8) {
    const float4v f0 = ((const float4v*)obs)[(size_t)n * 16 + g * 2];
    const float4v f1 = ((const float4v*)obs)[(size_t)n * 16 + g * 2 + 1];
    f[0]=f0[0]; f[1]=f0[1]; f[2]=f0[2]; f[3]=f0[3];
    f[4]=f1[0]; f[5]=f1[1]; f[6]=f1[2]; f[7]=f1[3];
  } else if (g < 10) {
    const float4v f0 = ((const float4v*)act)[(size_t)n * 4 + (g - 8) * 2];
    const float4v f1 = ((const float4v*)act)[(size_t)n * 4 + (g - 8) * 2 + 1];
    f[0]=f0[0]; f[1]=f0[1]; f[2]=f0[2]; f[3]=f0[3];
    f[4]=f1[0]; f[5]=f1[1]; f[6]=f1[2]; f[7]=f1[3];
  } else {
    #pragma unroll
    for (int i = 0; i < 8; ++i) f[i] = 0.f;
  }
  short8 o;
  #pragma unroll
  for (int i = 0; i < 8; ++i) o[i] = (short)f2bf(f[i]);
  *(short8*)(xb + (size_t)idx * 8) = o;
}

#define WE_N  (H_ * DPAD)            // 49152
#define WB_N  (H_ * H_)              // 262144
#define WO_N  (O_ * H_)              // 32768
#define PREP_TOT (WE_N + WB_N + WO_N + H_)

__global__ __launch_bounds__(256) void prep_w(
    const float* __restrict__ W_e, const float* __restrict__ W_B,
    const float* __restrict__ W_out, const float* __restrict__ a_raw,
    unsigned short* __restrict__ Web, unsigned short* __restrict__ WBb,
    unsigned short* __restrict__ Woutb, float* __restrict__ aarr,
    float* __restrict__ powa)
{
  const int idx = blockIdx.x * 256 + threadIdx.x;
  if (idx < WE_N) {
    const int h = idx / DPAD, d = idx % DPAD;
    Web[idx] = f2bf(d < DIN ? W_e[h * DIN + d] : 0.f);
  } else if (idx < WE_N + WB_N) {
    const int j = idx - WE_N;
    WBb[j] = f2bf(W_B[j]);
  } else if (idx < WE_N + WB_N + WO_N) {
    const int j = idx - (WE_N + WB_N);
    Woutb[j] = f2bf(W_out[j]);
  } else if (idx < PREP_TOT) {
    const int h = idx - (WE_N + WB_N + WO_N);
    const float a = tanhf(a_raw[h]);
    aarr[h] = a;
    float p = a;
    #pragma unroll
    for (int i = 0; i < 16; ++i) { powa[i * H_ + h] = p; p *= a; }  // a^(i+1)
  }
}

// ---------------------------------------------------------------------------
// Carry scan: serial over 32 chunks per (b,h). P[b,c,h] = carry INTO chunk c.
// ---------------------------------------------------------------------------
__global__ __launch_bounds__(256) void carry_scan(
    const float* __restrict__ e, float* __restrict__ P,
    const float* __restrict__ aarr)
{
  const int idx = blockIdx.x * 256 + threadIdx.x;  // B_*H_ = 8192
  const int b = idx >> 9, h = idx & (H_ - 1);
  const float a = aarr[h];
  float aL = a * a; aL *= aL; aL *= aL; aL *= aL; aL *= aL; aL *= aL;  // a^64
  float S = 0.f;
  for (int c = 0; c < C_; ++c) {
    const size_t o = ((size_t)(b * C_ + c)) * H_ + h;
    P[o] = S;
    S = fmaf(aL, S, e[o]);
  }
}

// ---------------------------------------------------------------------------
// Fused scan + out-projection. One block per chunk (512 blocks, 256 threads).
// Phase 1: diagonal scan of v over the 64-step chunk, init from P, writing
//          bf16 s-tile to XOR-swizzled LDS (row-major [64][512] would be a
//          16-way bank conflict on ds_read_b128 -> byte ^= (t&7)<<4, G4).
// Phase 2: y[64,64] = s[64,512] @ W_out[64,512]^T + b_out via MFMA; W_out
//          read from global (64KB, L2-hot across all 512 blocks).
// ---------------------------------------------------------------------------
__global__ __launch_bounds__(256) void scan_out(
    const unsigned int* __restrict__ v,      // bf16 pairs [BT, H/2]
    const float* __restrict__ P,             // [NCHUNK, H]
    const float* __restrict__ aarr,          // [H]
    const unsigned short* __restrict__ Wo,   // bf16 [O, H]
    const float* __restrict__ b_out,         // [O]
    float* __restrict__ y)                   // [BT, O] fp32
{
  __shared__ __align__(16) unsigned char sbytes[64 * 1024];
  const int blk = blockIdx.x;          // global chunk id = b*C + c
  const int tid = threadIdx.x;
  const int lane = tid & 63, w = tid >> 6;
  const int row_base = blk * L_;       // global token row of chunk start

  // Phase 1: scan. Thread owns h pair (2*tid, 2*tid+1).
  {
    const int h0 = tid * 2;
    const float a0 = aarr[h0], a1 = aarr[h0 + 1];
    float s0 = P[(size_t)blk * H_ + h0];
    float s1 = P[(size_t)blk * H_ + h0 + 1];
    const unsigned int* vp = v + (size_t)row_base * (H_ / 2) + tid;
    #pragma unroll 8
    for (int t = 0; t < L_; ++t) {
      const unsigned int pv = vp[(size_t)t * (H_ / 2)];
      s0 = fmaf(a0, s0, bf2f((unsigned short)(pv & 0xffff)));
      s1 = fmaf(a1, s1, bf2f((unsigned short)(pv >> 16)));
      const int byte = t * 1024 + ((tid * 4) ^ ((t & 7) << 4));
      *(unsigned int*)(sbytes + byte) =
          (unsigned int)f2bf(s0) | ((unsigned int)f2bf(s1) << 16);
    }
  }
  __syncthreads();

  // Phase 2: MFMA. Wave w: t-rows w*16..w*16+15, all 64 o-cols.
  f32x4 acc[4];
  #pragma unroll
  for (int n = 0; n < 4; ++n) acc[n] = f32x4{0.f, 0.f, 0.f, 0.f};
  const int r = w * 16 + (lane & 15);
  const int kof = (lane >> 4) * 8;
  #pragma unroll 4
  for (int k0 = 0; k0 < H_; k0 += 32) {
    const int byte = r * 1024 + (((k0 + kof) * 2) ^ ((r & 7) << 4));
    const short8 af = *(const short8*)(sbytes + byte);
    #pragma unroll
    for (int n = 0; n < 4; ++n) {
      const short8 bf = *(const short8*)(Wo + (size_t)(n * 16 + (lane & 15)) * H_ + k0 + kof);
      acc[n] = __builtin_amdgcn_mfma_f32_16x16x32_bf16(af, bf, acc[n], 0, 0, 0);
    }
  }
  const int cl = lane & 15, rg = (lane >> 4) * 4;
  #pragma unroll
  for (int n = 0; n < 4; ++n) {
    #pragma unroll
    for (int e2 = 0; e2 < 4; ++e2) {
      const int gr = row_base + w * 16 + rg + e2;
      const int gc = n * 16 + cl;
      y[(size_t)gr * O_ + gc] = acc[n][e2] + b_out[gc];
    }
  }
}

// ---------------------------------------------------------------------------
extern "C" void kernel_launch(void* const* d_in, const int* in_sizes, int n_in,
                              void* d_out, int out_size, void* d_ws, size_t ws_size,
                              hipStream_t stream)
{
  const float* obs   = (const float*)d_in[0];
  const float* act   = (const float*)d_in[1];
  const float* W_e   = (const float*)d_in[2];
  const float* b_e   = (const float*)d_in[3];
  const float* a_raw = (const float*)d_in[4];
  const float* W_B   = (const float*)d_in[5];
  const float* W_out = (const float*)d_in[6];
  const float* b_out = (const float*)d_in[7];
  float* y = (float*)d_out;

  char* w = (char*)d_ws;
  auto carve = [&](size_t bytes) {
    char* p = w; w += (bytes + 255) & ~(size_t)255; return p;
  };
  unsigned short* xb    = (unsigned short*)carve((size_t)BT_ * DPAD * 2);  // 6.3 MB
  unsigned short* Web   = (unsigned short*)carve((size_t)H_ * DPAD * 2);
  unsigned short* WBb   = (unsigned short*)carve((size_t)H_ * H_ * 2);
  unsigned short* Woutb = (unsigned short*)carve((size_t)O_ * H_ * 2);
  float*          aarr  = (float*)carve((size_t)H_ * 4);
  float*          powa  = (float*)carve((size_t)16 * H_ * 4);
  unsigned short* u     = (unsigned short*)carve((size_t)BT_ * H_ * 2);    // 33.5 MB
  unsigned short* v     = (unsigned short*)carve((size_t)BT_ * H_ * 2);    // 33.5 MB
  float*          e     = (float*)carve((size_t)NCHUNK * H_ * 4);
  float*          P     = (float*)carve((size_t)NCHUNK * H_ * 4);

  // Prep: concat+pad x -> bf16; weights -> bf16; a = tanh(a_raw); power table
  prep_x<<<BT_ * 12 / 256, 256, 0, stream>>>(obs, act, xb);
  prep_w<<<(PREP_TOT + 255) / 256, 256, 0, stream>>>(W_e, W_B, W_out, a_raw,
                                                     Web, WBb, Woutb, aarr, powa);
  // u = relu(x @ W_e^T + b_e)   [32768, 512], K=96 (padded)
  gemm_bt<128, 128, 32, 1, 1, 1, 0, 1><<<(BT_ / 128) * (H_ / 128), 256, 0, stream>>>(
      xb, Web, b_e, u, BT_, H_, DPAD, nullptr, nullptr);
  // v = u @ W_B^T               [32768, 512], K=512; epilogue also emits e
  gemm_bt<128, 128, 32, 0, 0, 1, 1, 1><<<(BT_ / 128) * (H_ / 128), 256, 0, stream>>>(
      u, WBb, nullptr, v, BT_, H_, H_, powa, e);
  // carries
  carry_scan<<<(B_ * H_) / 256, 256, 0, stream>>>(e, P, aarr);
  // fused scan + out-projection -> y
  scan_out<<<NCHUNK, 256, 0, stream>>>((const unsigned int*)v, P, aarr,
                                       Woutb, b_out, y);
}

// Round 4
// 79.029 us; speedup vs baseline: 1.3592x; 1.0032x over previous
//
#include <hip/hip_runtime.h>
#include <hip/hip_bf16.h>

// Problem constants
#define B_    16
#define T_    2048
#define H_    512
#define BT_   32768      // B*T tokens
#define DIN   80         // obs 64 + act 16
#define DPAD  96         // padded K for embed GEMM (3 x 32)
#define L_    64         // scan chunk length
#define C_    32         // chunks per batch (T/L)
#define O_    64         // output dim
#define NCHUNK (BT_ / L_)  // 512 total chunks

typedef __attribute__((ext_vector_type(8))) short short8;
typedef __attribute__((ext_vector_type(4))) float f32x4;
typedef __attribute__((ext_vector_type(4))) float float4v;

__device__ __forceinline__ float bf2f(unsigned short u) {
  union { unsigned int i; float f; } x; x.i = ((unsigned int)u) << 16; return x.f;
}
__device__ __forceinline__ unsigned short f2bf(float f) {
  union { float f; unsigned int i; } x; x.f = f;
  unsigned int r = x.i + 0x7fffu + ((x.i >> 16) & 1u);
  return (unsigned short)(r >> 16);
}

// ---------------------------------------------------------------------------
// bf16 MFMA GEMM, full-N tile: C[M,N] = A[M,K] @ Bt[N,K]^T (+bias/ReLU).
// BM=128, BN=512 (entire N), BK=32. 512 threads = 8 waves in 2Mx4N; each
// wave owns 64x128 (FM=4 x FN=8 16x16 frags) -> 32 MFMA per 12 ds_read_b128
// per K-step. 2-phase double-buffered global_load_lds pipeline (verified
// structure from R3): stage tile t+1 before computing tile t, one
// __syncthreads per K-step. grid = M/128 blocks (256 -> 1 per CU, no tail).
// Full-N => each A-panel is read by exactly one block (A HBM traffic once).
// CE=1: emit chunk-end weighted sums e[chunk][h]; each wave owns exactly one
// 64-row chunk (WM=64).
// ---------------------------------------------------------------------------
template<int RELU, int BIAS, int CE>
__global__ __launch_bounds__(512) void gemm_fn(
    const unsigned short* __restrict__ A, const unsigned short* __restrict__ Bt,
    const float* __restrict__ bias, unsigned short* __restrict__ Cb,
    int K,
    const float* __restrict__ powa,   // [16][H]: a^(i+1), i=0..15  (CE only)
    float* __restrict__ e)            // [NCHUNK][H]                (CE only)
{
  constexpr int BM = 128, BN = 512, BK = 32;
  constexpr int A_BYTES = BM * BK * 2;         // 8192
  constexpr int TOT = A_BYTES + BN * BK * 2;   // 40960
  constexpr int ROUNDS = TOT / (512 * 16);     // 5
  __shared__ __align__(16) unsigned char ldsb[2 * TOT];   // 80 KB

  const int tid  = threadIdx.x;
  const int lane = tid & 63;
  const int wid  = tid >> 6;
  const int wr   = wid >> 2;          // 0..1  (M)
  const int wc   = wid & 3;           // 0..3  (N)
  const int row0 = (int)blockIdx.x * BM;

  auto stage = [&](int k0, int buf) {
    #pragma unroll
    for (int r = 0; r < ROUNDS; ++r) {
      const int o = r * 8192 + tid * 16;     // byte offset within one buffer
      const unsigned short* gsrc;
      if (o < A_BYTES) {                      // round 0 exactly covers A
        const int idx = o >> 1;
        const int row = idx / BK, kk = idx % BK;
        gsrc = A + (size_t)(row0 + row) * K + (k0 + kk);
      } else {
        const int idx = (o - A_BYTES) >> 1;
        const int row = idx / BK, kk = idx % BK;
        gsrc = Bt + (size_t)row * K + (k0 + kk);
      }
      __builtin_amdgcn_global_load_lds(
          (const __attribute__((address_space(1))) void*)gsrc,
          (__attribute__((address_space(3))) void*)(ldsb + buf * TOT + o),
          16, 0, 0);
    }
  };

  f32x4 acc[4][8];
  #pragma unroll
  for (int m = 0; m < 4; ++m)
    #pragma unroll
    for (int n = 0; n < 8; ++n) acc[m][n] = f32x4{0.f, 0.f, 0.f, 0.f};

  const int NT = K / BK;
  stage(0, 0);
  __syncthreads();
  int cur = 0;
  for (int t = 0; t < NT; ++t) {
    if (t + 1 < NT) stage((t + 1) * BK, cur ^ 1);   // prefetch next tile

    const unsigned short* base = (const unsigned short*)(ldsb + cur * TOT);
    const unsigned short* pA = base + (wr * 64 + (lane & 15)) * BK + ((lane >> 4) * 8);
    const unsigned short* pB = base + (A_BYTES / 2) + (wc * 128 + (lane & 15)) * BK + ((lane >> 4) * 8);
    short8 af[4];
    #pragma unroll
    for (int m = 0; m < 4; ++m) af[m] = *(const short8*)(pA + m * 16 * BK);
    #pragma unroll
    for (int n = 0; n < 8; ++n) {
      const short8 bfr = *(const short8*)(pB + n * 16 * BK);
      #pragma unroll
      for (int m = 0; m < 4; ++m)
        acc[m][n] = __builtin_amdgcn_mfma_f32_16x16x32_bf16(af[m], bfr, acc[m][n], 0, 0, 0);
    }

    __syncthreads();   // drains vmcnt(0): prefetch of t+1 now resident
    cur ^= 1;
  }

  // Epilogue. D[r][c]: c = lane&15, r = (lane>>4)*4 + e2  (m89-verified)
  const int cl = lane & 15, rg = (lane >> 4) * 4;
  #pragma unroll
  for (int m = 0; m < 4; ++m) {
    #pragma unroll
    for (int n = 0; n < 8; ++n) {
      #pragma unroll
      for (int e2 = 0; e2 < 4; ++e2) {
        const int gr = row0 + wr * 64 + m * 16 + rg + e2;
        const int gc = wc * 128 + n * 16 + cl;
        float v = acc[m][n][e2];
        if (BIAS) v += bias[gc];
        if (RELU) v = fmaxf(v, 0.f);
        Cb[(size_t)gr * BN + gc] = f2bf(v);
      }
    }
  }

  // Chunk-end e[chunk][h] = sum_{i=0..63} a^{63-i} * v_i; wave owns one
  // 64-row chunk. a^{63-i} = a^{15-rg-e2} * (a^16)^{3-m}, i = m*16+rg+e2.
  if (CE) {
    const int chunk = (row0 + wr * 64) >> 6;
    #pragma unroll
    for (int n = 0; n < 8; ++n) {
      const int h = wc * 128 + n * 16 + cl;
      const float a16 = powa[15 * H_ + h];
      float ep = 0.f;
      #pragma unroll
      for (int e2 = 0; e2 < 4; ++e2) {
        const int k = 15 - rg - e2;    // 0..15
        const float wk = (k == 0) ? 1.f : powa[(size_t)(k - 1) * H_ + h];
        float hsum = acc[0][n][e2];                 // Horner over m
        hsum = fmaf(hsum, a16, acc[1][n][e2]);
        hsum = fmaf(hsum, a16, acc[2][n][e2]);
        hsum = fmaf(hsum, a16, acc[3][n][e2]);
        ep = fmaf(wk, hsum, ep);
      }
      ep += __shfl_xor(ep, 16);
      ep += __shfl_xor(ep, 32);
      if ((lane >> 4) == 0)
        e[(size_t)chunk * H_ + h] = ep;
    }
  }
}

// ---------------------------------------------------------------------------
// Fused prep: x concat+pad -> bf16 (part 1), weights -> bf16 + a/power table
// (part 2). One kernel, ranges split by flat thread index.
// ---------------------------------------------------------------------------
#define PX_N  (BT_ * 12)             // 393216 threads, 8 bf16 each
#define WE_N  (H_ * DPAD)            // 49152
#define WB_N  (H_ * H_)              // 262144
#define WO_N  (O_ * H_)              // 32768
#define PW_N  (WE_N + WB_N + WO_N + H_)
#define PREP_THREADS (PX_N + PW_N)   // 737792 = 2882 * 256 exactly

__global__ __launch_bounds__(256) void prep(
    const float* __restrict__ obs, const float* __restrict__ act,
    const float* __restrict__ W_e, const float* __restrict__ W_B,
    const float* __restrict__ W_out, const float* __restrict__ a_raw,
    unsigned short* __restrict__ xb,
    unsigned short* __restrict__ Web, unsigned short* __restrict__ WBb,
    unsigned short* __restrict__ Woutb, float* __restrict__ aarr,
    float* __restrict__ powa)
{
  const int gid = blockIdx.x * 256 + threadIdx.x;
  if (gid < PX_N) {
    const int g = gid % 12, n = gid / 12;
    float f[8];
    if (g < 8) {
      const float4v f0 = ((const float4v*)obs)[(size_t)n * 16 + g * 2];
      const float4v f1 = ((const float4v*)obs)[(size_t)n * 16 + g * 2 + 1];
      f[0]=f0[0]; f[1]=f0[1]; f[2]=f0[2]; f[3]=f0[3];
      f[4]=f1[0]; f[5]=f1[1]; f[6]=f1[2]; f[7]=f1[3];
    } else if (g < 10) {
      const float4v f0 = ((const float4v*)act)[(size_t)n * 4 + (g - 8) * 2];
      const float4v f1 = ((const float4v*)act)[(size_t)n * 4 + (g - 8) * 2 + 1];
      f[0]=f0[0]; f[1]=f0[1]; f[2]=f0[2]; f[3]=f0[3];
      f[4]=f1[0]; f[5]=f1[1]; f[6]=f1[2]; f[7]=f1[3];
    } else {
      #pragma unroll
      for (int i = 0; i < 8; ++i) f[i] = 0.f;
    }
    short8 o;
    #pragma unroll
    for (int i = 0; i < 8; ++i) o[i] = (short)f2bf(f[i]);
    *(short8*)(xb + (size_t)gid * 8) = o;
    return;
  }
  const int idx = gid - PX_N;
  if (idx < WE_N) {
    const int h = idx / DPAD, d = idx % DPAD;
    Web[idx] = f2bf(d < DIN ? W_e[h * DIN + d] : 0.f);
  } else if (idx < WE_N + WB_N) {
    const int j = idx - WE_N;
    WBb[j] = f2bf(W_B[j]);
  } else if (idx < WE_N + WB_N + WO_N) {
    const int j = idx - (WE_N + WB_N);
    Woutb[j] = f2bf(W_out[j]);
  } else if (idx < PW_N) {
    const int h = idx - (WE_N + WB_N + WO_N);
    const float a = tanhf(a_raw[h]);
    aarr[h] = a;
    float p = a;
    #pragma unroll
    for (int i = 0; i < 16; ++i) { powa[i * H_ + h] = p; p *= a; }  // a^(i+1)
  }
}

// ---------------------------------------------------------------------------
// Fused carry + scan + out-projection. One block per chunk (512 blocks).
// Phase 0: inline carry — P[h] = Horner over predecessors' chunk-ends e
//          (e is 1 MB, L2-hot; <=31 iterations of 8B/thread).
// Phase 1: diagonal scan of v over the 64-step chunk, init from P, writing
//          bf16 s-tile to XOR-swizzled LDS (row-major [64][512] would be a
//          16-way bank conflict on ds_read_b128 -> byte ^= (t&7)<<4, G4).
// Phase 2: y[64,64] = s[64,512] @ W_out[64,512]^T + b_out via MFMA; W_out
//          read from global (64KB, L2-hot across all 512 blocks).
// ---------------------------------------------------------------------------
__global__ __launch_bounds__(256) void scan_out(
    const unsigned int* __restrict__ v,      // bf16 pairs [BT, H/2]
    const float* __restrict__ e,             // [NCHUNK, H] chunk-end sums
    const float* __restrict__ aarr,          // [H]
    const unsigned short* __restrict__ Wo,   // bf16 [O, H]
    const float* __restrict__ b_out,         // [O]
    float* __restrict__ y)                   // [BT, O] fp32
{
  __shared__ __align__(16) unsigned char sbytes[64 * 1024];
  const int blk = blockIdx.x;          // global chunk id = b*C + c
  const int b = blk >> 5, c = blk & 31;
  const int tid = threadIdx.x;
  const int lane = tid & 63, w = tid >> 6;
  const int row_base = blk * L_;       // global token row of chunk start

  // Phase 0+1: carry + scan. Thread owns h pair (2*tid, 2*tid+1).
  {
    const int h0 = tid * 2;
    const float a0 = aarr[h0], a1 = aarr[h0 + 1];
    float aL0 = a0 * a0, aL1 = a1 * a1;                    // a^2
    aL0 *= aL0; aL1 *= aL1;                                // a^4
    aL0 *= aL0; aL1 *= aL1;                                // a^8
    aL0 *= aL0; aL1 *= aL1;                                // a^16
    aL0 *= aL0; aL1 *= aL1;                                // a^32
    aL0 *= aL0; aL1 *= aL1;                                // a^64
    float s0 = 0.f, s1 = 0.f;                              // carry into chunk
    for (int j = 0; j < c; ++j) {
      const size_t o = ((size_t)(b * C_ + j)) * H_ + h0;
      s0 = fmaf(aL0, s0, e[o]);
      s1 = fmaf(aL1, s1, e[o + 1]);
    }
    const unsigned int* vp = v + (size_t)row_base * (H_ / 2) + tid;
    #pragma unroll 8
    for (int t = 0; t < L_; ++t) {
      const unsigned int pv = vp[(size_t)t * (H_ / 2)];
      s0 = fmaf(a0, s0, bf2f((unsigned short)(pv & 0xffff)));
      s1 = fmaf(a1, s1, bf2f((unsigned short)(pv >> 16)));
      const int byte = t * 1024 + ((tid * 4) ^ ((t & 7) << 4));
      *(unsigned int*)(sbytes + byte) =
          (unsigned int)f2bf(s0) | ((unsigned int)f2bf(s1) << 16);
    }
  }
  __syncthreads();

  // Phase 2: MFMA. Wave w: t-rows w*16..w*16+15, all 64 o-cols.
  f32x4 acc[4];
  #pragma unroll
  for (int n = 0; n < 4; ++n) acc[n] = f32x4{0.f, 0.f, 0.f, 0.f};
  const int r = w * 16 + (lane & 15);
  const int kof = (lane >> 4) * 8;
  #pragma unroll 4
  for (int k0 = 0; k0 < H_; k0 += 32) {
    const int byte = r * 1024 + (((k0 + kof) * 2) ^ ((r & 7) << 4));
    const short8 af = *(const short8*)(sbytes + byte);
    #pragma unroll
    for (int n = 0; n < 4; ++n) {
      const short8 bf = *(const short8*)(Wo + (size_t)(n * 16 + (lane & 15)) * H_ + k0 + kof);
      acc[n] = __builtin_amdgcn_mfma_f32_16x16x32_bf16(af, bf, acc[n], 0, 0, 0);
    }
  }
  const int cl = lane & 15, rg = (lane >> 4) * 4;
  #pragma unroll
  for (int n = 0; n < 4; ++n) {
    #pragma unroll
    for (int e2 = 0; e2 < 4; ++e2) {
      const int gr = row_base + w * 16 + rg + e2;
      const int gc = n * 16 + cl;
      y[(size_t)gr * O_ + gc] = acc[n][e2] + b_out[gc];
    }
  }
}

// ---------------------------------------------------------------------------
extern "C" void kernel_launch(void* const* d_in, const int* in_sizes, int n_in,
                              void* d_out, int out_size, void* d_ws, size_t ws_size,
                              hipStream_t stream)
{
  const float* obs   = (const float*)d_in[0];
  const float* act   = (const float*)d_in[1];
  const float* W_e   = (const float*)d_in[2];
  const float* b_e   = (const float*)d_in[3];
  const float* a_raw = (const float*)d_in[4];
  const float* W_B   = (const float*)d_in[5];
  const float* W_out = (const float*)d_in[6];
  const float* b_out = (const float*)d_in[7];
  float* y = (float*)d_out;

  char* w = (char*)d_ws;
  auto carve = [&](size_t bytes) {
    char* p = w; w += (bytes + 255) & ~(size_t)255; return p;
  };
  unsigned short* xb    = (unsigned short*)carve((size_t)BT_ * DPAD * 2);  // 6.3 MB
  unsigned short* Web   = (unsigned short*)carve((size_t)H_ * DPAD * 2);
  unsigned short* WBb   = (unsigned short*)carve((size_t)H_ * H_ * 2);
  unsigned short* Woutb = (unsigned short*)carve((size_t)O_ * H_ * 2);
  float*          aarr  = (float*)carve((size_t)H_ * 4);
  float*          powa  = (float*)carve((size_t)16 * H_ * 4);
  unsigned short* u     = (unsigned short*)carve((size_t)BT_ * H_ * 2);    // 33.5 MB
  unsigned short* v     = (unsigned short*)carve((size_t)BT_ * H_ * 2);    // 33.5 MB
  float*          e     = (float*)carve((size_t)NCHUNK * H_ * 4);          // 1 MB

  // 1) prep: x concat+pad, weight bf16 casts, tanh + power table
  prep<<<PREP_THREADS / 256, 256, 0, stream>>>(obs, act, W_e, W_B, W_out,
                                               a_raw, xb, Web, WBb, Woutb,
                                               aarr, powa);
  // 2) u = relu(x @ W_e^T + b_e)   [32768, 512], K=96 (padded)
  gemm_fn<1, 1, 0><<<BT_ / 128, 512, 0, stream>>>(
      xb, Web, b_e, u, DPAD, nullptr, nullptr);
  // 3) v = u @ W_B^T               [32768, 512], K=512; epilogue emits e
  gemm_fn<0, 0, 1><<<BT_ / 128, 512, 0, stream>>>(
      u, WBb, nullptr, v, H_, powa, e);
  // 4) fused carry + scan + out-projection -> y
  scan_out<<<NCHUNK, 256, 0, stream>>>((const unsigned int*)v, e, aarr,
                                       Woutb, b_out, y);
}